// Round 15
// baseline (1145.155 us; speedup 1.0000x reference)
//
#include <hip/hip_runtime.h>
#include <hip/hip_bf16.h>
#include <hip/hip_fp16.h>
#include <hip/hip_cooperative_groups.h>

namespace cg = cooperative_groups;

// ============================================================================
// GCN forward as ONE persistent cooperative kernel (7 phases, grid.sync()
// between). Eliminates 6 kernel-boundary drains/gaps of the R12 pipeline.
// Phase bodies are the R10/R12-proven structures:
//   - CSR-by-dst via fixed-capacity bucketed counting sort (no hist/scan).
//   - fused gather+dense layers, 8 lanes/node: register gather accumulation
//     (R11: LDS atomics 10x slow; R13: coop-coalescing regresses), octet
//     __shfl_xor combines, conflict-free LDS weights (ds_read_b128/b64).
// Algebra: A_hat(xW) = (A_hat x)W;  out[d] = dinv[d]*(sum hs[s] + hs[d]) + b,
// hs = h*dinv[row] folded into previous dense epilogue. hs tables fp16.
// ============================================================================

#define NBUCK_SHIFT 8            // 256 nodes per bucket
#define CAP         8192         // bucket capacity (avg 4096, sigma ~64)
#define PART_CHUNK  4096         // edges per partition chunk (256 thr x 16)

// ---------------- helpers ----------------
__device__ inline float4 pack8_dev(const float* v) {
    float4 out;
    __half2* h2 = reinterpret_cast<__half2*>(&out);
#pragma unroll
    for (int j = 0; j < 4; ++j) h2[j] = __floats2half2_rn(v[2 * j], v[2 * j + 1]);
    return out;
}
__device__ inline void acc8(float* acc, float4 raw) {
    const __half2* h2 = reinterpret_cast<const __half2*>(&raw);
#pragma unroll
    for (int j = 0; j < 4; ++j) {
        float2 v = __half22float2(h2[j]);
        acc[2 * j]     += v.x;
        acc[2 * j + 1] += v.y;
    }
}

__global__ __launch_bounds__(256, 4) void gcn_fused(
    const float* __restrict__ x, const int* __restrict__ src, const int* __restrict__ dst,
    const float* __restrict__ W1, const float* __restrict__ b1,
    const float* __restrict__ W2, const float* __restrict__ b2,
    const float* __restrict__ W3, const float* __restrict__ b3,
    const float* __restrict__ W4, const float* __restrict__ b4,
    int* __restrict__ gcur, unsigned int* __restrict__ bucketed,
    int2* __restrict__ ends, float* __restrict__ dinv, int* __restrict__ sorted_src,
    __half* __restrict__ xs, __half* __restrict__ h2s, __half* __restrict__ h3s,
    __half* __restrict__ h4s, float* __restrict__ out,
    int n, int E, int nbuck) {
    cg::grid_group grid = cg::this_grid();
    __shared__ __align__(16) char smem_raw[3264 * 4];   // 13056B, max phase need
    float* smemf = reinterpret_cast<float*>(smem_raw);
    int*   smemi = reinterpret_cast<int*>(smem_raw);
    const int t = threadIdx.x;
    const long long nthreads = (long long)gridDim.x * 256;
    const long long gtid0 = (long long)blockIdx.x * 256 + t;

    // ================= phase 0: init bucket cursors =================
    for (int i = (int)gtid0; i < nbuck; i += (int)nthreads) gcur[i] = i * CAP;
    __threadfence();
    grid.sync();

    // ================= phase 1: partition edges into buckets =================
    {
        int* cnt = smemi;          // 512
        int* bb  = smemi + 512;    // 512
        const int nchunk = (E + PART_CHUNK - 1) / PART_CHUNK;
        for (int c = blockIdx.x; c < nchunk; c += gridDim.x) {
            for (int i = t; i < 512; i += 256) cnt[i] = 0;
            __syncthreads();
            long long start = (long long)c * PART_CHUNK;
            int sv[16], dv[16], bv[16];
#pragma unroll
            for (int k = 0; k < 16; ++k) {
                long long e = start + (long long)k * 256 + t;
                bool ok = e < E;
                sv[k] = ok ? src[e] : 0;
                dv[k] = ok ? dst[e] : 0;
                bv[k] = ok ? (dv[k] >> NBUCK_SHIFT) : -1;
                if (ok) atomicAdd(&cnt[bv[k]], 1);
            }
            __syncthreads();
            for (int i = t; i < nbuck; i += 256) {
                int cc = cnt[i];
                bb[i] = cc ? atomicAdd(&gcur[i], cc) : 0;
            }
            __syncthreads();
            for (int i = t; i < 512; i += 256) cnt[i] = 0;   // running cursor
            __syncthreads();
#pragma unroll
            for (int k = 0; k < 16; ++k) {
                if (bv[k] >= 0) {
                    int pos = bb[bv[k]] + atomicAdd(&cnt[bv[k]], 1);
                    bucketed[pos] = ((unsigned int)sv[k] << 8) | (unsigned int)(dv[k] & 255);
                }
            }
            __syncthreads();
        }
    }
    __threadfence();
    grid.sync();

    // ================= phase 2: CSR finalize + xs scale/pad =================
    {
        int* ldeg  = smemi;        // 256
        int* lscan = smemi + 256;  // 256
        for (int b = blockIdx.x; b < nbuck; b += gridDim.x) {
            const int beg = b * CAP;
            const int end = gcur[b];
            ldeg[t] = 0;
            __syncthreads();
            for (int e = beg + t; e < end; e += 256)
                atomicAdd(&ldeg[bucketed[e] & 255u], 1);
            __syncthreads();
            int v = ldeg[t];
            lscan[t] = v;
            __syncthreads();
            for (int off = 1; off < 256; off <<= 1) {
                int xv = (t >= off) ? lscan[t - off] : 0;
                __syncthreads();
                lscan[t] += xv;
                __syncthreads();
            }
            int excl = lscan[t] - v;
            int node = (b << NBUCK_SHIFT) + t;
            float di = rsqrtf((float)v + 1.0f);      // +1 self-loop
            if (node < n) {
                ends[node] = make_int2(beg + excl, beg + excl + v);
                dinv[node] = di;
                const float* xr = x + (long long)node * 18;
                float vv[32];
#pragma unroll
                for (int k = 0; k < 18; ++k) vv[k] = xr[k] * di;
#pragma unroll
                for (int k = 18; k < 32; ++k) vv[k] = 0.0f;
                float4* o = reinterpret_cast<float4*>(xs + (long long)node * 32);
                o[0] = pack8_dev(vv);
                o[1] = pack8_dev(vv + 8);
                o[2] = pack8_dev(vv + 16);
                o[3] = pack8_dev(vv + 24);
            }
            __syncthreads();
            lscan[t] = beg + excl;                   // placement cursor
            __syncthreads();
            for (int e = beg + t; e < end; e += 256) {
                unsigned int pk = bucketed[e];
                int pos = atomicAdd(&lscan[pk & 255u], 1);
                sorted_src[pos] = (int)(pk >> 8);
            }
            __syncthreads();
        }
    }
    __threadfence();
    grid.sync();

    // ================= phase 3: layer 1+2 fused =================
    {
        float* sW1 = smemf;            // 1152
        float* sB1 = smemf + 1152;     // 64
        float* sW2 = smemf + 1216;     // 2048
        for (int i = t; i < 18 * 64; i += 256) sW1[i] = W1[i];
        for (int i = t; i < 64; i += 256) sB1[i] = b1[i];
        for (int i = t; i < 64 * 32; i += 256) sW2[i] = W2[i];
        __syncthreads();
        const float4* sW1v = reinterpret_cast<const float4*>(sW1);
        const float4* sW2v = reinterpret_cast<const float4*>(sW2);

        for (long long gt = gtid0; gt < 8LL * n; gt += nthreads) {
            int node = (int)(gt >> 3);
            int l8   = (int)(gt & 7);
            int2 be = ends[node];
            float di = dinv[node];

            float acc[24];
#pragma unroll
            for (int j = 0; j < 24; ++j) acc[j] = 0.0f;
            if (l8 == 7) {
                const float4* pp = reinterpret_cast<const float4*>(xs + (long long)node * 32);
                acc8(acc, pp[0]); acc8(acc + 8, pp[1]); acc8(acc + 16, pp[2]);
            }
            for (int e = be.x + l8; e < be.y; e += 8) {
                int s = sorted_src[e];
                const float4* pp = reinterpret_cast<const float4*>(xs + (long long)s * 32);
                acc8(acc, pp[0]); acc8(acc + 8, pp[1]); acc8(acc + 16, pp[2]);
            }
#pragma unroll
            for (int j = 0; j < 18; ++j) {
                acc[j] += __shfl_xor(acc[j], 1);
                acc[j] += __shfl_xor(acc[j], 2);
                acc[j] += __shfl_xor(acc[j], 4);
                acc[j] *= di;
            }

            float hid[8];
#pragma unroll
            for (int jj = 0; jj < 8; ++jj) hid[jj] = sB1[l8 * 8 + jj];
#pragma unroll
            for (int k = 0; k < 18; ++k) {
                float ak = acc[k];
#pragma unroll
                for (int q = 0; q < 2; ++q) {
                    float4 w = sW1v[k * 16 + l8 * 2 + q];
                    hid[4 * q]     = fmaf(ak, w.x, hid[4 * q]);
                    hid[4 * q + 1] = fmaf(ak, w.y, hid[4 * q + 1]);
                    hid[4 * q + 2] = fmaf(ak, w.z, hid[4 * q + 2]);
                    hid[4 * q + 3] = fmaf(ak, w.w, hid[4 * q + 3]);
                }
            }
#pragma unroll
            for (int jj = 0; jj < 8; ++jj) hid[jj] = fmaxf(hid[jj], 0.0f);

            float o4[4] = {0.0f, 0.0f, 0.0f, 0.0f};
#pragma unroll
            for (int jj = 0; jj < 8; ++jj) {
                float hv[8];
                hv[0] = hid[jj];
#pragma unroll
                for (int m = 1; m < 8; ++m) hv[m] = __shfl_xor(hv[0], m);
#pragma unroll
                for (int m = 0; m < 8; ++m) {
                    int j = (l8 ^ m) * 8 + jj;
                    float4 w = sW2v[j * 8 + l8];
                    o4[0] = fmaf(hv[m], w.x, o4[0]);
                    o4[1] = fmaf(hv[m], w.y, o4[1]);
                    o4[2] = fmaf(hv[m], w.z, o4[2]);
                    o4[3] = fmaf(hv[m], w.w, o4[3]);
                }
            }
            union { float2 f2; __half2 h2[2]; } u;
            u.h2[0] = __floats2half2_rn(o4[0] * di, o4[1] * di);
            u.h2[1] = __floats2half2_rn(o4[2] * di, o4[3] * di);
            *reinterpret_cast<float2*>(h2s + (long long)node * 32 + l8 * 4) = u.f2;
        }
    }
    __threadfence();
    grid.sync();

    // ================= phase 4: layer 3 fused =================
    {
        float* sW3 = smemf;            // 512
        float* sB2 = smemf + 512;      // 32
        for (int i = t; i < 32 * 16; i += 256) sW3[i] = W3[i];
        for (int i = t; i < 32; i += 256) sB2[i] = b2[i];
        __syncthreads();
        const float2* sW3v = reinterpret_cast<const float2*>(sW3);

        for (long long gt = gtid0; gt < 8LL * n; gt += nthreads) {
            int node = (int)(gt >> 3);
            int l8   = (int)(gt & 7);
            int2 be = ends[node];
            float di = dinv[node];

            float acc[32];
#pragma unroll
            for (int j = 0; j < 32; ++j) acc[j] = 0.0f;
            if (l8 == 7) {
                const float4* pp = reinterpret_cast<const float4*>(h2s + (long long)node * 32);
                acc8(acc, pp[0]); acc8(acc + 8, pp[1]); acc8(acc + 16, pp[2]); acc8(acc + 24, pp[3]);
            }
            for (int e = be.x + l8; e < be.y; e += 8) {
                int s = sorted_src[e];
                const float4* pp = reinterpret_cast<const float4*>(h2s + (long long)s * 32);
                acc8(acc, pp[0]); acc8(acc + 8, pp[1]); acc8(acc + 16, pp[2]); acc8(acc + 24, pp[3]);
            }
            const bool hi4 = (l8 & 4);
            float h16[16];
#pragma unroll
            for (int v = 0; v < 16; ++v) {
                float keep = hi4 ? acc[16 + v] : acc[v];
                float send = hi4 ? acc[v] : acc[16 + v];
                h16[v] = keep + __shfl_xor(send, 4);
            }
            const bool hi2 = (l8 & 2);
            float h8[8];
#pragma unroll
            for (int v = 0; v < 8; ++v) {
                float keep = hi2 ? h16[8 + v] : h16[v];
                float send = hi2 ? h16[v] : h16[8 + v];
                h8[v] = keep + __shfl_xor(send, 2);
            }
            const bool hi1 = (l8 & 1);
            float k4[4];
#pragma unroll
            for (int v = 0; v < 4; ++v) {
                float keep = hi1 ? h8[4 + v] : h8[v];
                float send = hi1 ? h8[v] : h8[4 + v];
                k4[v] = keep + __shfl_xor(send, 1);
            }

            const int k0 = l8 * 4;
            float o0 = 0.0f, o1 = 0.0f;
#pragma unroll
            for (int kk = 0; kk < 4; ++kk) {
                float vv[8];
                vv[0] = fmaxf(fmaf(k4[kk], di, sB2[k0 + kk]), 0.0f);
#pragma unroll
                for (int m = 1; m < 8; ++m) vv[m] = __shfl_xor(vv[0], m);
#pragma unroll
                for (int m = 0; m < 8; ++m) {
                    int k = (l8 ^ m) * 4 + kk;
                    float2 w = sW3v[k * 8 + l8];
                    o0 = fmaf(vv[m], w.x, o0);
                    o1 = fmaf(vv[m], w.y, o1);
                }
            }
            *reinterpret_cast<__half2*>(h3s + (long long)node * 16 + l8 * 2) =
                __floats2half2_rn(o0 * di, o1 * di);
        }
    }
    __threadfence();
    grid.sync();

    // ================= phase 5: layer 4 fused =================
    {
        float* sW4 = smemf;        // 32
        float* sB3 = smemf + 32;   // 16
        for (int i = t; i < 32; i += 256) sW4[i] = W4[i];
        for (int i = t; i < 16; i += 256) sB3[i] = b3[i];
        __syncthreads();

        for (long long gt = gtid0; gt < 8LL * n; gt += nthreads) {
            int node = (int)(gt >> 3);
            int l8   = (int)(gt & 7);
            int2 be = ends[node];
            float di = dinv[node];

            float acc[16];
#pragma unroll
            for (int j = 0; j < 16; ++j) acc[j] = 0.0f;
            if (l8 == 7) {
                const float4* pp = reinterpret_cast<const float4*>(h3s + (long long)node * 16);
                acc8(acc, pp[0]); acc8(acc + 8, pp[1]);
            }
            for (int e = be.x + l8; e < be.y; e += 8) {
                int s = sorted_src[e];
                const float4* pp = reinterpret_cast<const float4*>(h3s + (long long)s * 16);
                acc8(acc, pp[0]); acc8(acc + 8, pp[1]);
            }
            const bool hi4 = (l8 & 4);
            float h8[8];
#pragma unroll
            for (int v = 0; v < 8; ++v) {
                float keep = hi4 ? acc[8 + v] : acc[v];
                float send = hi4 ? acc[v] : acc[8 + v];
                h8[v] = keep + __shfl_xor(send, 4);
            }
            const bool hi2 = (l8 & 2);
            float h4v[4];
#pragma unroll
            for (int v = 0; v < 4; ++v) {
                float keep = hi2 ? h8[4 + v] : h8[v];
                float send = hi2 ? h8[v] : h8[4 + v];
                h4v[v] = keep + __shfl_xor(send, 2);
            }
            const bool hi1 = (l8 & 1);
            float k2[2];
#pragma unroll
            for (int v = 0; v < 2; ++v) {
                float keep = hi1 ? h4v[2 + v] : h4v[v];
                float send = hi1 ? h4v[v] : h4v[2 + v];
                k2[v] = keep + __shfl_xor(send, 1);
            }
            const int k0 = l8 * 2;
            float o0 = 0.0f, o1 = 0.0f;
#pragma unroll
            for (int kk = 0; kk < 2; ++kk) {
                float v = fmaxf(fmaf(k2[kk], di, sB3[k0 + kk]), 0.0f);
                o0 = fmaf(v, sW4[2 * (k0 + kk)], o0);
                o1 = fmaf(v, sW4[2 * (k0 + kk) + 1], o1);
            }
            o0 += __shfl_xor(o0, 1); o0 += __shfl_xor(o0, 2); o0 += __shfl_xor(o0, 4);
            o1 += __shfl_xor(o1, 1); o1 += __shfl_xor(o1, 2); o1 += __shfl_xor(o1, 4);
            if (l8 == 0)
                *reinterpret_cast<__half2*>(h4s + 2LL * node) = __floats2half2_rn(o0 * di, o1 * di);
        }
    }
    __threadfence();
    grid.sync();

    // ================= phase 6: final aggregation + log_softmax =================
    {
        const float lb0 = b4[0], lb1 = b4[1];
        for (long long gt = gtid0; gt < 8LL * n; gt += nthreads) {
            int node = (int)(gt >> 3);
            int l8   = (int)(gt & 7);
            int2 be = ends[node];
            float ax = 0.0f, ay = 0.0f;
            if (l8 == 7) {
                float2 r = __half22float2(*reinterpret_cast<const __half2*>(h4s + 2LL * node));
                ax += r.x; ay += r.y;
            }
            for (int e = be.x + l8; e < be.y; e += 8) {
                int s = sorted_src[e];
                float2 r = __half22float2(*reinterpret_cast<const __half2*>(h4s + 2LL * s));
                ax += r.x; ay += r.y;
            }
            ax += __shfl_xor(ax, 1); ax += __shfl_xor(ax, 2); ax += __shfl_xor(ax, 4);
            ay += __shfl_xor(ay, 1); ay += __shfl_xor(ay, 2); ay += __shfl_xor(ay, 4);
            if (l8 == 0) {
                float di = dinv[node];
                float a = ax * di + lb0;
                float c = ay * di + lb1;
                float m = fmaxf(a, c);
                float lse = m + logf(expf(a - m) + expf(c - m));
                *reinterpret_cast<float2*>(out + 2LL * node) = make_float2(a - lse, c - lse);
            }
        }
    }
}

static inline char* align16(char* p) { return (char*)(((uintptr_t)p + 15) & ~(uintptr_t)15); }

extern "C" void kernel_launch(void* const* d_in, const int* in_sizes, int n_in,
                              void* d_out, int out_size, void* d_ws, size_t ws_size,
                              hipStream_t stream) {
    (void)n_in; (void)out_size; (void)ws_size;

    const float* x  = (const float*)d_in[0];      // [N,18]
    const int*   ei = (const int*)d_in[1];        // [2,E]
    const float* W1 = (const float*)d_in[2];
    const float* b1 = (const float*)d_in[3];
    const float* W2 = (const float*)d_in[4];
    const float* b2 = (const float*)d_in[5];
    const float* W3 = (const float*)d_in[6];
    const float* b3 = (const float*)d_in[7];
    const float* W4 = (const float*)d_in[8];
    const float* b4 = (const float*)d_in[9];

    int n = in_sizes[0] / 18;                     // 100000
    int E = in_sizes[1] / 2;                      // 1600000
    const int* src = ei;
    const int* dst = ei + E;
    int nbuck = (n + 255) >> NBUCK_SHIFT;         // 391

    // ---- workspace layout (16B-aligned regions) ----
    char* p = (char*)d_ws;
    int*    gcur       = (int*)p;            p = align16(p + 512 * 4);
    int2*   ends       = (int2*)p;           p = align16(p + (size_t)n * 8);
    float*  dinv       = (float*)p;          p = align16(p + (size_t)n * 4);
    int*    sorted_src = (int*)p;            p = align16(p + (size_t)nbuck * CAP * 4);
    unsigned int* bucketed = (unsigned int*)p; p = align16(p + (size_t)nbuck * CAP * 4);
    __half* xs         = (__half*)p;         p = align16(p + (size_t)n * 32 * 2);
    __half* h2s        = (__half*)p;         p = align16(p + (size_t)n * 32 * 2);
    __half* h3s        = (__half*)p;         p = align16(p + (size_t)n * 16 * 2);
    __half* h4s        = (__half*)p;         p = align16(p + (size_t)n * 2 * 2);
    float*  out        = (float*)d_out;

    // cooperative grid: all blocks co-resident (256 CUs, occupancy-capped)
    int maxb = 4;
    hipOccupancyMaxActiveBlocksPerMultiprocessor(&maxb, (const void*)gcn_fused, 256, 0);
    if (maxb < 1) maxb = 1;
    if (maxb > 8) maxb = 8;
    int grid_blocks = maxb * 256;

    void* args[] = {
        (void*)&x, (void*)&src, (void*)&dst,
        (void*)&W1, (void*)&b1, (void*)&W2, (void*)&b2,
        (void*)&W3, (void*)&b3, (void*)&W4, (void*)&b4,
        (void*)&gcur, (void*)&bucketed, (void*)&ends, (void*)&dinv, (void*)&sorted_src,
        (void*)&xs, (void*)&h2s, (void*)&h3s, (void*)&h4s, (void*)&out,
        (void*)&n, (void*)&E, (void*)&nbuck
    };
    hipLaunchCooperativeKernel((const void*)gcn_fused, dim3(grid_blocks), dim3(256),
                               args, 0, stream);
}